// Round 1
// baseline (49.413 us; speedup 1.0000x reference)
//
#include <hip/hip_runtime.h>

// Problem constants (from reference setup_inputs): B=16, N=4096, n_u=n_v=64.
#define BB 16
#define NN 4096
#define NCODE 4096   // 64*64 codes per batch
#define WEIGHT 0.1f

// One wave (64 lanes) per point. Lane i holds u_logits[p][i] and v_logits[p][i].
// Butterfly argmax with first-index tie-break (matches jnp.argmax).
__global__ __launch_bounds__(256) void uniq_hist_kernel(
    const float* __restrict__ u_logits,
    const float* __restrict__ v_logits,
    const int* __restrict__ mask,
    unsigned int* __restrict__ hist)
{
    const int gid  = blockIdx.x * blockDim.x + threadIdx.x;
    const int p    = gid >> 6;          // point index in [0, B*N)
    const int lane = gid & 63;

    const float* up = u_logits + (size_t)p * 64;
    const float* vp = v_logits + (size_t)p * 64;

    float uv = up[lane]; int ui = lane;
    float vv = vp[lane]; int vi = lane;

    #pragma unroll
    for (int off = 32; off > 0; off >>= 1) {
        float ouv = __shfl_xor(uv, off, 64);
        int   oui = __shfl_xor(ui, off, 64);
        if (ouv > uv || (ouv == uv && oui < ui)) { uv = ouv; ui = oui; }
        float ovv = __shfl_xor(vv, off, 64);
        int   ovi = __shfl_xor(vi, off, 64);
        if (ovv > vv || (ovv == vv && ovi < vi)) { vv = ovv; vi = ovi; }
    }

    // All lanes hold the converged (max, first-index); lane 0 commits.
    if (lane == 0 && mask[p] != 0 && ui > 0 && vi > 0) {
        const int b = p >> 12;          // p / N
        atomicAdd(&hist[(b << 12) + (ui << 6) + vi], 1u);
    }
}

// Single-block exact integer reduction over all B*NCODE bins.
__global__ __launch_bounds__(1024) void uniq_reduce_kernel(
    const unsigned int* __restrict__ hist,
    float* __restrict__ out)
{
    __shared__ long long wave_sums[16];

    long long acc = 0;
    for (int i = threadIdx.x; i < BB * NCODE; i += 1024) {
        const long long c = (long long)hist[i];
        acc += c * (c - 1);             // ordered duplicate pairs in this bin
    }

    #pragma unroll
    for (int off = 32; off > 0; off >>= 1)
        acc += __shfl_xor(acc, off, 64);

    const int wid = threadIdx.x >> 6;
    if ((threadIdx.x & 63) == 0) wave_sums[wid] = acc;
    __syncthreads();

    if (threadIdx.x == 0) {
        long long total = 0;
        #pragma unroll
        for (int w = 0; w < 16; ++w) total += wave_sums[w];
        // loss = WEIGHT * ( (total/2) / B )
        out[0] = (float)total * (WEIGHT / (2.0f * (float)BB));
    }
}

extern "C" void kernel_launch(void* const* d_in, const int* in_sizes, int n_in,
                              void* d_out, int out_size, void* d_ws, size_t ws_size,
                              hipStream_t stream) {
    const float* u_logits = (const float*)d_in[0];
    const float* v_logits = (const float*)d_in[1];
    const int*   mask     = (const int*)d_in[2];
    float*        out  = (float*)d_out;
    unsigned int* hist = (unsigned int*)d_ws;

    // Zero the per-batch histograms (256 KB).
    hipMemsetAsync(d_ws, 0, (size_t)BB * NCODE * sizeof(unsigned int), stream);

    // B*N points, one wave each, 4 waves per 256-thread block.
    const int n_points = BB * NN;
    uniq_hist_kernel<<<n_points / 4, 256, 0, stream>>>(u_logits, v_logits, mask, hist);

    uniq_reduce_kernel<<<1, 1024, 0, stream>>>(hist, out);
}

// Round 2
// 36.821 us; speedup vs baseline: 1.3420x; 1.3420x over previous
//
#include <hip/hip_runtime.h>

// Problem constants (from reference setup_inputs): B=16, N=4096, n_u=n_v=64.
#define BB 16
#define NN 4096
#define NCODE 4096   // 64*64 codes per batch
#define WEIGHT 0.1f

// Zero the B*NCODE uint histogram (256 KB) with uint4 stores.
// 64 blocks x 256 threads x 16B = 256 KB exactly.
__global__ __launch_bounds__(256) void uniq_zero_kernel(uint4* __restrict__ hist4)
{
    const int i = blockIdx.x * blockDim.x + threadIdx.x;
    hist4[i] = make_uint4(0u, 0u, 0u, 0u);
}

// One wave (64 lanes) per point. Lane i holds u_logits[p][i] and v_logits[p][i].
// Butterfly argmax with first-index tie-break (matches jnp.argmax).
__global__ __launch_bounds__(256) void uniq_hist_kernel(
    const float* __restrict__ u_logits,
    const float* __restrict__ v_logits,
    const int* __restrict__ mask,
    unsigned int* __restrict__ hist)
{
    const int gid  = blockIdx.x * blockDim.x + threadIdx.x;
    const int p    = gid >> 6;          // point index in [0, B*N)
    const int lane = gid & 63;

    const float* up = u_logits + (size_t)p * 64;
    const float* vp = v_logits + (size_t)p * 64;

    float uv = up[lane]; int ui = lane;
    float vv = vp[lane]; int vi = lane;

    #pragma unroll
    for (int off = 32; off > 0; off >>= 1) {
        float ouv = __shfl_xor(uv, off, 64);
        int   oui = __shfl_xor(ui, off, 64);
        if (ouv > uv || (ouv == uv && oui < ui)) { uv = ouv; ui = oui; }
        float ovv = __shfl_xor(vv, off, 64);
        int   ovi = __shfl_xor(vi, off, 64);
        if (ovv > vv || (ovv == vv && ovi < vi)) { vv = ovv; vi = ovi; }
    }

    // All lanes hold the converged (max, first-index); lane 0 commits.
    if (lane == 0 && mask[p] != 0 && ui > 0 && vi > 0) {
        const int b = p >> 12;          // p / N
        atomicAdd(&hist[(b << 12) + (ui << 6) + vi], 1u);
    }
}

// Single-block exact integer reduction over all B*NCODE bins (uint4 reads).
__global__ __launch_bounds__(1024) void uniq_reduce_kernel(
    const uint4* __restrict__ hist4,
    float* __restrict__ out)
{
    __shared__ long long wave_sums[16];

    long long acc = 0;
    // B*NCODE/4 = 16384 uint4; 1024 threads -> 16 uint4 each.
    for (int i = threadIdx.x; i < (BB * NCODE) / 4; i += 1024) {
        const uint4 c4 = hist4[i];
        acc += (long long)c4.x * (c4.x - 1);
        acc += (long long)c4.y * (c4.y - 1);
        acc += (long long)c4.z * (c4.z - 1);
        acc += (long long)c4.w * (c4.w - 1);
    }

    #pragma unroll
    for (int off = 32; off > 0; off >>= 1)
        acc += __shfl_xor(acc, off, 64);

    const int wid = threadIdx.x >> 6;
    if ((threadIdx.x & 63) == 0) wave_sums[wid] = acc;
    __syncthreads();

    if (threadIdx.x == 0) {
        long long total = 0;
        #pragma unroll
        for (int w = 0; w < 16; ++w) total += wave_sums[w];
        // loss = WEIGHT * ( (total/2) / B )
        out[0] = (float)total * (WEIGHT / (2.0f * (float)BB));
    }
}

extern "C" void kernel_launch(void* const* d_in, const int* in_sizes, int n_in,
                              void* d_out, int out_size, void* d_ws, size_t ws_size,
                              hipStream_t stream) {
    const float* u_logits = (const float*)d_in[0];
    const float* v_logits = (const float*)d_in[1];
    const int*   mask     = (const int*)d_in[2];
    float*        out  = (float*)d_out;
    unsigned int* hist = (unsigned int*)d_ws;

    // Zero the per-batch histograms (256 KB) with our own kernel:
    // hipMemsetAsync-in-graph measured 41 us/replay (fillBufferAligned at
    // 6.5 GB/s) -- custom uint4 zero kernel is ~2 us.
    uniq_zero_kernel<<<64, 256, 0, stream>>>((uint4*)hist);

    // B*N points, one wave each, 4 waves per 256-thread block.
    const int n_points = BB * NN;
    uniq_hist_kernel<<<n_points / 4, 256, 0, stream>>>(u_logits, v_logits, mask, hist);

    uniq_reduce_kernel<<<1, 1024, 0, stream>>>((const uint4*)hist, out);
}

// Round 3
// 28.842 us; speedup vs baseline: 1.7133x; 1.2767x over previous
//
#include <hip/hip_runtime.h>

// Problem constants (from reference setup_inputs): B=16, N=4096, n_u=n_v=64.
#define BB 16
#define NN 4096
#define NPTS (BB * NN)      // 65536 points
#define NCODE 4096          // 64*64 codes per batch
#define WEIGHT 0.1f
#define INVALID_CODE 0xFFFFu

// K1: one wave (64 lanes) per point. Lane i holds u_logits[p][i], v_logits[p][i].
// Butterfly argmax with first-index tie-break (matches jnp.argmax), then lane 0
// writes a u16 code (u*64+v) or INVALID. Also zeroes the 2-word control block.
__global__ __launch_bounds__(256) void uniq_code_kernel(
    const float* __restrict__ u_logits,
    const float* __restrict__ v_logits,
    const int* __restrict__ mask,
    unsigned short* __restrict__ codes,
    unsigned long long* __restrict__ ctrl)
{
    const int gid  = blockIdx.x * blockDim.x + threadIdx.x;
    const int p    = gid >> 6;          // point index in [0, B*N)
    const int lane = gid & 63;

    if (gid < 2) ctrl[gid] = 0ULL;      // acc, done-counter (K2 runs after K1)

    const float* up = u_logits + (size_t)p * 64;
    const float* vp = v_logits + (size_t)p * 64;

    float uv = up[lane]; int ui = lane;
    float vv = vp[lane]; int vi = lane;

    #pragma unroll
    for (int off = 32; off > 0; off >>= 1) {
        float ouv = __shfl_xor(uv, off, 64);
        int   oui = __shfl_xor(ui, off, 64);
        if (ouv > uv || (ouv == uv && oui < ui)) { uv = ouv; ui = oui; }
        float ovv = __shfl_xor(vv, off, 64);
        int   ovi = __shfl_xor(vi, off, 64);
        if (ovv > vv || (ovv == vv && ovi < vi)) { vv = ovv; vi = ovi; }
    }

    if (lane == 0) {
        unsigned short code = (unsigned short)INVALID_CODE;
        if (mask[p] != 0 && ui > 0 && vi > 0)
            code = (unsigned short)((ui << 6) | vi);
        codes[p] = code;                // unconditional write: no stale state
    }
}

// K2: one block per batch. LDS histogram over 4096 codes, Sum c*(c-1) local,
// then device-atomic combine; the last block to finish writes out[0].
__global__ __launch_bounds__(1024) void uniq_batch_kernel(
    const unsigned short* __restrict__ codes,
    unsigned long long* __restrict__ ctrl,
    float* __restrict__ out)
{
    __shared__ unsigned int h[NCODE];       // 16 KB
    __shared__ long long wave_sums[16];

    const int t = threadIdx.x;
    const int b = blockIdx.x;

    #pragma unroll
    for (int i = t; i < NCODE; i += 1024) h[i] = 0u;
    __syncthreads();

    // Read this batch's 4096 codes as uints (2 codes per load).
    const unsigned int* cb = (const unsigned int*)(codes + (size_t)b * NN);
    #pragma unroll
    for (int i = t; i < NN / 2; i += 1024) {
        const unsigned int w  = cb[i];
        const unsigned int c0 = w & 0xFFFFu;
        const unsigned int c1 = w >> 16;
        if (c0 != INVALID_CODE) atomicAdd(&h[c0], 1u);
        if (c1 != INVALID_CODE) atomicAdd(&h[c1], 1u);
    }
    __syncthreads();

    long long acc = 0;
    #pragma unroll
    for (int i = t; i < NCODE; i += 1024) {
        const long long c = (long long)h[i];
        acc += c * (c - 1);                 // ordered duplicate pairs
    }

    #pragma unroll
    for (int off = 32; off > 0; off >>= 1)
        acc += __shfl_xor(acc, off, 64);

    if ((t & 63) == 0) wave_sums[t >> 6] = acc;
    __syncthreads();

    if (t == 0) {
        long long partial = 0;
        #pragma unroll
        for (int w = 0; w < 16; ++w) partial += wave_sums[w];
        atomicAdd(&ctrl[0], (unsigned long long)partial);
        __threadfence();
        const unsigned long long old = atomicAdd(&ctrl[1], 1ULL);
        if (old == (unsigned long long)(BB - 1)) {
            // All 16 partials are in (each add precedes its fenced done-inc).
            const unsigned long long total = atomicAdd(&ctrl[0], 0ULL);
            out[0] = (float)total * (WEIGHT / (2.0f * (float)BB));
        }
    }
}

extern "C" void kernel_launch(void* const* d_in, const int* in_sizes, int n_in,
                              void* d_out, int out_size, void* d_ws, size_t ws_size,
                              hipStream_t stream) {
    const float* u_logits = (const float*)d_in[0];
    const float* v_logits = (const float*)d_in[1];
    const int*   mask     = (const int*)d_in[2];
    float* out = (float*)d_out;

    unsigned short* codes = (unsigned short*)d_ws;                       // 128 KB
    unsigned long long* ctrl = (unsigned long long*)((char*)d_ws + 131072); // 16 B

    // K1: B*N points, one wave each, 4 waves per 256-thread block.
    uniq_code_kernel<<<NPTS / 4, 256, 0, stream>>>(u_logits, v_logits, mask,
                                                   codes, ctrl);
    // K2: one block per batch; last block writes the scalar.
    uniq_batch_kernel<<<BB, 1024, 0, stream>>>(codes, ctrl, out);
}